// Round 9
// baseline (1363.643 us; speedup 1.0000x reference)
//
#include <hip/hip_runtime.h>
#include <hip/hip_bf16.h>
#include <stdint.h>

typedef __bf16 bf16;
typedef __attribute__((ext_vector_type(8))) __bf16 bf16x8;
typedef __attribute__((ext_vector_type(4))) float f32x4;

// dtype map (forensically locked, round 9):
//   ALL inputs fp32 (rounds 1-3/7 NaN on bf16 reads + round-8 detector unanimous).
//   OUTPUT fp32 (round 4-8 scramble signature = packed-bf16 read as fp32).
//   Comparison ref is bf16-rounded (threshold 2% of bf16(max|ref|)).

// ---------------- K1: row degree -> dis = deg>0 ? rsqrt(deg) : 0 ----------------
__global__ __launch_bounds__(256) void k_dis(const float* __restrict__ adj1,
                                             const float* __restrict__ adj2,
                                             float* __restrict__ dis) {
  int t = threadIdx.x;
  int wave = t >> 6, lane = t & 63;
  int gw = blockIdx.x * 4 + wave;  // 0..8191
  int mat = gw >> 12;
  int row = gw & 4095;
  const float* A = mat ? adj2 : adj1;
  const f32x4* Arow = (const f32x4*)(A + (size_t)row * 4096);
  float s = 0.f;
#pragma unroll
  for (int it = 0; it < 16; ++it) {
    int j0 = it * 256 + lane * 4;
    f32x4 v = Arow[it * 64 + lane];
#pragma unroll
    for (int k = 0; k < 4; ++k) s += ((j0 + k) == row) ? 0.f : v[k];
  }
#pragma unroll
  for (int off = 32; off >= 1; off >>= 1) s += __shfl_down(s, off, 64);
  if (lane == 0) dis[mat * 4096 + row] = (s > 0.f) ? (1.0f / sqrtf(s)) : 0.f;
}

// ---------------- K2: sparse prop rows: P[i, which*256 + c] = -(Ahat x0)[i,c] ----------------
#define CAP 2048
__global__ __launch_bounds__(256) void k_spmm(const float* __restrict__ adj1,
                                              const float* __restrict__ adj2,
                                              const float* __restrict__ x,
                                              const float* __restrict__ dis,
                                              bf16* __restrict__ P) {
  __shared__ int s_idx[CAP];
  __shared__ float s_val[CAP];
  __shared__ int s_cnt;
  int t = threadIdx.x;
  int row = blockIdx.x;
  int which = blockIdx.y;
  const float* A = which ? adj2 : adj1;
  const float* dsel = dis + which * 4096;
  if (t == 0) s_cnt = 0;
  __syncthreads();
  const f32x4* Arow = (const f32x4*)(A + (size_t)row * 4096);
#pragma unroll
  for (int it = 0; it < 4; ++it) {
    int idx = it * 256 + t;
    int j0 = idx * 4;
    f32x4 v = Arow[idx];
#pragma unroll
    for (int k = 0; k < 4; ++k) {
      float f = v[k];
      int j = j0 + k;
      if (f != 0.f && j != row) {
        int pos = atomicAdd(&s_cnt, 1);
        if (pos < CAP) { s_idx[pos] = j; s_val[pos] = f * dsel[j]; }
      }
    }
  }
  __syncthreads();
  int n = s_cnt; if (n > CAP) n = CAP;
  float acc = 0.f;
  for (int e = 0; e < n; ++e) {
    int j = s_idx[e];
    acc += s_val[e] * x[(size_t)j * 256 + t];  // x0 = first 4096 flat rows
  }
  float prop = -dsel[row] * acc;
  P[(size_t)row * 512 + (size_t)which * 256 + t] = (bf16)prop;
}

// ---------------- K_naive: exact reference mirror, fp32 in / fp32 out ----------------
// one block per flat row; thread t = channel index.
__global__ __launch_bounds__(256) void k_naive(const float* __restrict__ X,
                                               const bf16* __restrict__ P,
                                               const float* __restrict__ W0a,
                                               const float* __restrict__ W1a,
                                               const float* __restrict__ bca,
                                               const float* __restrict__ W0b,
                                               const float* __restrict__ W1b,
                                               const float* __restrict__ bcb,
                                               const float* __restrict__ Wp,
                                               const float* __restrict__ bp,
                                               float* __restrict__ out) {
  __shared__ float xs[256];
  __shared__ float ps[512];
  __shared__ float U[512];
  int t = threadIdx.x;
  int row = blockIdx.x;  // 0..32767
  bool hasP = (row < 4096);

  if (t < 64) {
    f32x4 v = *(const f32x4*)(X + (size_t)row * 256 + t * 4);
#pragma unroll
    for (int k = 0; k < 4; ++k) xs[t * 4 + k] = v[k];
  }
  if (t >= 64 && t < 128) {
    int i = t - 64;  // 0..63 covers 512
    if (hasP) {
      bf16x8 v = *(const bf16x8*)(P + (size_t)row * 512 + i * 8);
#pragma unroll
      for (int k = 0; k < 8; ++k) ps[i * 8 + k] = (float)v[k];
    } else {
#pragma unroll
      for (int k = 0; k < 8; ++k) ps[i * 8 + k] = 0.f;
    }
  }
  __syncthreads();

  // U[t]     = (x@W0a)[t] + prop1@W1a + bca[t]
  // U[t+256] = (x@W0b)[t] + prop2@W1b + bcb[t]
  float ua = bca[t], ub = bcb[t];
#pragma unroll 4
  for (int c = 0; c < 256; ++c) {
    float xv = xs[c];
    ua += xv * W0a[(size_t)c * 256 + t];
    ub += xv * W0b[(size_t)c * 256 + t];
  }
  if (hasP) {
#pragma unroll 4
    for (int c = 0; c < 256; ++c) {
      ua += ps[c] * W1a[(size_t)c * 256 + t];
      ub += ps[c + 256] * W1b[(size_t)c * 256 + t];
    }
  }
  U[t] = ua;
  U[t + 256] = ub;
  __syncthreads();

  float acc = bp[t];
#pragma unroll 4
  for (int m = 0; m < 512; ++m) acc += U[m] * Wp[(size_t)m * 256 + t];
  out[(size_t)row * 256 + t] = acc;  // fp32 output
}

extern "C" void kernel_launch(void* const* d_in, const int* in_sizes, int n_in,
                              void* d_out, int out_size, void* d_ws, size_t ws_size,
                              hipStream_t stream) {
  const float* x    = (const float*)d_in[0];
  const float* adj1 = (const float*)d_in[1];
  const float* adj2 = (const float*)d_in[2];
  const float* W0a  = (const float*)d_in[3];
  const float* W1a  = (const float*)d_in[4];
  const float* bca  = (const float*)d_in[5];
  const float* W0b  = (const float*)d_in[6];
  const float* W1b  = (const float*)d_in[7];
  const float* bcb  = (const float*)d_in[8];
  const float* Wp   = (const float*)d_in[9];
  const float* bp   = (const float*)d_in[10];
  float* out = (float*)d_out;

  char* ws = (char*)d_ws;
  float* dis = (float*)(ws);              // 2*4096 f32 = 32 KB
  bf16*  P   = (bf16*)(ws + 64 * 1024);   // 4096*512 bf16 = 4 MB

  k_dis<<<dim3(2048), dim3(256), 0, stream>>>(adj1, adj2, dis);
  k_spmm<<<dim3(4096, 2), dim3(256), 0, stream>>>(adj1, adj2, x, dis, P);
  k_naive<<<dim3(32768), dim3(256), 0, stream>>>(x, P, W0a, W1a, bca, W0b, W1b, bcb,
                                                 Wp, bp, out);
}

// Round 10
// 304.613 us; speedup vs baseline: 4.4766x; 4.4766x over previous
//
#include <hip/hip_runtime.h>
#include <hip/hip_bf16.h>
#include <stdint.h>

typedef __bf16 bf16;
typedef __attribute__((ext_vector_type(8))) __bf16 bf16x8;
typedef __attribute__((ext_vector_type(4))) float f32x4;

// dtype map (locked round 9): ALL inputs fp32, output fp32.

// ---------------- K1: row degree -> dis = deg>0 ? rsqrt(deg) : 0 ----------------
__global__ __launch_bounds__(256) void k_dis(const float* __restrict__ adj1,
                                             const float* __restrict__ adj2,
                                             float* __restrict__ dis) {
  int t = threadIdx.x;
  int wave = t >> 6, lane = t & 63;
  int gw = blockIdx.x * 4 + wave;  // 0..8191
  int mat = gw >> 12;
  int row = gw & 4095;
  const float* A = mat ? adj2 : adj1;
  const f32x4* Arow = (const f32x4*)(A + (size_t)row * 4096);
  float s = 0.f;
#pragma unroll
  for (int it = 0; it < 16; ++it) {
    int j0 = it * 256 + lane * 4;
    f32x4 v = Arow[it * 64 + lane];
#pragma unroll
    for (int k = 0; k < 4; ++k) s += ((j0 + k) == row) ? 0.f : v[k];
  }
#pragma unroll
  for (int off = 32; off >= 1; off >>= 1) s += __shfl_down(s, off, 64);
  if (lane == 0) dis[mat * 4096 + row] = (s > 0.f) ? (1.0f / sqrtf(s)) : 0.f;
}

// ---------------- K2: sparse prop rows: P[i, which*256 + c] = -(Ahat x0)[i,c] ----------------
#define CAP 2048
__global__ __launch_bounds__(256) void k_spmm(const float* __restrict__ adj1,
                                              const float* __restrict__ adj2,
                                              const float* __restrict__ x,
                                              const float* __restrict__ dis,
                                              bf16* __restrict__ P) {
  __shared__ int s_idx[CAP];
  __shared__ float s_val[CAP];
  __shared__ int s_cnt;
  int t = threadIdx.x;
  int row = blockIdx.x;
  int which = blockIdx.y;
  const float* A = which ? adj2 : adj1;
  const float* dsel = dis + which * 4096;
  if (t == 0) s_cnt = 0;
  __syncthreads();
  const f32x4* Arow = (const f32x4*)(A + (size_t)row * 4096);
#pragma unroll
  for (int it = 0; it < 4; ++it) {
    int idx = it * 256 + t;
    int j0 = idx * 4;
    f32x4 v = Arow[idx];
#pragma unroll
    for (int k = 0; k < 4; ++k) {
      float f = v[k];
      int j = j0 + k;
      if (f != 0.f && j != row) {
        int pos = atomicAdd(&s_cnt, 1);
        if (pos < CAP) { s_idx[pos] = j; s_val[pos] = f * dsel[j]; }
      }
    }
  }
  __syncthreads();
  int n = s_cnt; if (n > CAP) n = CAP;
  float acc = 0.f;
  for (int e = 0; e < n; ++e) {
    int j = s_idx[e];
    acc += s_val[e] * x[(size_t)j * 256 + t];  // x0 = first 4096 flat rows
  }
  float prop = -dsel[row] * acc;
  P[(size_t)row * 512 + (size_t)which * 256 + t] = (bf16)prop;
}

// ---------------- K3: weight folding (fp32 in, bf16 transposed out) ----------------
// WxT[o][c]   = sum_m W0a[c][m]*Wp[m][o] + W0b[c][m]*Wp[256+m][o]
// WextT[o][k] : k<256 -> (W1a@Wp_top)^T ; k>=256 -> (W1b@Wp_bot)^T
// biasv[o]    = bc_a@Wp_top + bc_b@Wp_bot + bp
__global__ __launch_bounds__(256) void k_wprep(const float* __restrict__ W0a,
                                               const float* __restrict__ W1a,
                                               const float* __restrict__ bca,
                                               const float* __restrict__ W0b,
                                               const float* __restrict__ W1b,
                                               const float* __restrict__ bcb,
                                               const float* __restrict__ Wp,
                                               const float* __restrict__ bp,
                                               bf16* __restrict__ WxT,
                                               bf16* __restrict__ WextT,
                                               float* __restrict__ biasv) {
  __shared__ float wt[256], wb[256], red[256];
  int t = threadIdx.x;
  int o = blockIdx.x;
  wt[t] = Wp[(size_t)t * 256 + o];
  wb[t] = Wp[(size_t)(t + 256) * 256 + o];
  __syncthreads();
  const f32x4* r0a = (const f32x4*)(W0a + (size_t)t * 256);
  const f32x4* r0b = (const f32x4*)(W0b + (size_t)t * 256);
  const f32x4* r1a = (const f32x4*)(W1a + (size_t)t * 256);
  const f32x4* r1b = (const f32x4*)(W1b + (size_t)t * 256);
  float ax = 0.f, a1 = 0.f, a2 = 0.f;
  for (int c = 0; c < 64; ++c) {
    f32x4 va = r0a[c], vb = r0b[c], v1 = r1a[c], v2 = r1b[c];
#pragma unroll
    for (int k = 0; k < 4; ++k) {
      int m = c * 4 + k;
      ax += va[k] * wt[m] + vb[k] * wb[m];
      a1 += v1[k] * wt[m];
      a2 += v2[k] * wb[m];
    }
  }
  WxT[(size_t)o * 256 + t] = (bf16)ax;
  WextT[(size_t)o * 512 + t] = (bf16)a1;
  WextT[(size_t)o * 512 + 256 + t] = (bf16)a2;
  red[t] = bca[t] * wt[t] + bcb[t] * wb[t];
  __syncthreads();
  for (int s2 = 128; s2 > 0; s2 >>= 1) {
    if (t < s2) red[t] += red[t + s2];
    __syncthreads();
  }
  if (t == 0) biasv[o] = red[0] + bp[o];
}

// ---------------- K4: fused GEMM out = x@Wx (+ P@Wext rows<4096) + biasv ----------------
// 128x128 tile, 4 waves (2x2 of 64x64), mfma 16x16x32 bf16, fp32 out.
__device__ __forceinline__ void mfma_tile(const char* ldsA, const char* ldsB,
                                          int wm, int wn, int lr, int quad,
                                          f32x4 acc[4][4]) {
  bf16x8 af[4], bb[4];
#pragma unroll
  for (int mf = 0; mf < 4; ++mf)
    af[mf] = *(const bf16x8*)(ldsA + ((wm * 64 + mf * 16 + lr) * 64 + quad * 16));
#pragma unroll
  for (int nf = 0; nf < 4; ++nf)
    bb[nf] = *(const bf16x8*)(ldsB + ((wn * 64 + nf * 16 + lr) * 64 + quad * 16));
#pragma unroll
  for (int mf = 0; mf < 4; ++mf)
#pragma unroll
    for (int nf = 0; nf < 4; ++nf)
      acc[mf][nf] = __builtin_amdgcn_mfma_f32_16x16x32_bf16(af[mf], bb[nf], acc[mf][nf], 0, 0, 0);
}

__global__ __launch_bounds__(256, 2) void k_gemm(const float* __restrict__ X,
                                                 const bf16* __restrict__ P,
                                                 const bf16* __restrict__ WxT,
                                                 const bf16* __restrict__ WextT,
                                                 const float* __restrict__ biasv,
                                                 float* __restrict__ out) {
  __shared__ __attribute__((aligned(16))) char ldsA[8192];
  __shared__ __attribute__((aligned(16))) char ldsB[8192];
  int t = threadIdx.x;
  int lane = t & 63, wave = t >> 6;
  int wm = wave & 1, wn = wave >> 1;
  int lr = lane & 15, quad = lane >> 4;
  int R0 = blockIdx.y * 128;  // M tile
  int N0 = blockIdx.x * 128;  // N tile

  f32x4 acc[4][4];
#pragma unroll
  for (int i = 0; i < 4; ++i)
#pragma unroll
    for (int j = 0; j < 4; ++j) acc[i][j] = (f32x4){0.f, 0.f, 0.f, 0.f};

  int srow = t >> 2;        // 0..63
  int scol = (t & 3) * 8;   // bf16 col offset within the 32-wide K slab

#pragma unroll 1
  for (int step = 0; step < 8; ++step) {  // K=256 over x / WxT
    int kb = step * 32;
    const float* xp0 = X + (size_t)(R0 + srow) * 256 + kb + scol;
    const float* xp1 = X + (size_t)(R0 + srow + 64) * 256 + kb + scol;
    f32x4 f00 = *(const f32x4*)(xp0), f01 = *(const f32x4*)(xp0 + 4);
    f32x4 f10 = *(const f32x4*)(xp1), f11 = *(const f32x4*)(xp1 + 4);
    bf16x8 a0, a1;
#pragma unroll
    for (int k = 0; k < 4; ++k) {
      a0[k] = (bf16)f00[k]; a0[k + 4] = (bf16)f01[k];
      a1[k] = (bf16)f10[k]; a1[k + 4] = (bf16)f11[k];
    }
    bf16x8 b0 = *(const bf16x8*)(WxT + (size_t)(N0 + srow) * 256 + kb + scol);
    bf16x8 b1 = *(const bf16x8*)(WxT + (size_t)(N0 + srow + 64) * 256 + kb + scol);
    __syncthreads();
    *(bf16x8*)(ldsA + t * 16) = a0;
    *(bf16x8*)(ldsA + 4096 + t * 16) = a1;
    *(bf16x8*)(ldsB + t * 16) = b0;
    *(bf16x8*)(ldsB + 4096 + t * 16) = b1;
    __syncthreads();
    mfma_tile(ldsA, ldsB, wm, wn, lr, quad, acc);
  }

  if (R0 < 4096) {  // prop terms, faithful to the :n bug
#pragma unroll 1
    for (int step = 0; step < 16; ++step) {  // K=512 over P / WextT
      int kb = step * 32;
      bf16x8 a0 = *(const bf16x8*)(P + (size_t)(R0 + srow) * 512 + kb + scol);
      bf16x8 a1 = *(const bf16x8*)(P + (size_t)(R0 + srow + 64) * 512 + kb + scol);
      bf16x8 b0 = *(const bf16x8*)(WextT + (size_t)(N0 + srow) * 512 + kb + scol);
      bf16x8 b1 = *(const bf16x8*)(WextT + (size_t)(N0 + srow + 64) * 512 + kb + scol);
      __syncthreads();
      *(bf16x8*)(ldsA + t * 16) = a0;
      *(bf16x8*)(ldsA + 4096 + t * 16) = a1;
      *(bf16x8*)(ldsB + t * 16) = b0;
      *(bf16x8*)(ldsB + 4096 + t * 16) = b1;
      __syncthreads();
      mfma_tile(ldsA, ldsB, wm, wn, lr, quad, acc);
    }
  }

  // epilogue: C/D layout col=lane&15, row=quad*4+reg ; fp32 stores
#pragma unroll
  for (int nf = 0; nf < 4; ++nf) {
    int ocol = N0 + wn * 64 + nf * 16 + lr;
    float bv = biasv[ocol];
#pragma unroll
    for (int mf = 0; mf < 4; ++mf) {
      int orow = R0 + wm * 64 + mf * 16 + quad * 4;
#pragma unroll
      for (int r = 0; r < 4; ++r)
        out[(size_t)(orow + r) * 256 + ocol] = acc[mf][nf][r] + bv;
    }
  }
}

extern "C" void kernel_launch(void* const* d_in, const int* in_sizes, int n_in,
                              void* d_out, int out_size, void* d_ws, size_t ws_size,
                              hipStream_t stream) {
  const float* x    = (const float*)d_in[0];
  const float* adj1 = (const float*)d_in[1];
  const float* adj2 = (const float*)d_in[2];
  const float* W0a  = (const float*)d_in[3];
  const float* W1a  = (const float*)d_in[4];
  const float* bca  = (const float*)d_in[5];
  const float* W0b  = (const float*)d_in[6];
  const float* W1b  = (const float*)d_in[7];
  const float* bcb  = (const float*)d_in[8];
  const float* Wp   = (const float*)d_in[9];
  const float* bp   = (const float*)d_in[10];
  float* out = (float*)d_out;

  char* ws = (char*)d_ws;
  float* dis   = (float*)(ws);               // 2*4096 f32 = 32 KB
  float* biasv = (float*)(ws + 32 * 1024);   // 1 KB
  bf16*  WxT   = (bf16*)(ws + 64 * 1024);    // 256*256 bf16 = 128 KB
  bf16*  WextT = (bf16*)(ws + 320 * 1024);   // 256*512 bf16 = 256 KB
  bf16*  P     = (bf16*)(ws + 704 * 1024);   // 4096*512 bf16 = 4 MB

  k_dis<<<dim3(2048), dim3(256), 0, stream>>>(adj1, adj2, dis);
  k_wprep<<<dim3(256), dim3(256), 0, stream>>>(W0a, W1a, bca, W0b, W1b, bcb, Wp, bp,
                                               WxT, WextT, biasv);
  k_spmm<<<dim3(4096, 2), dim3(256), 0, stream>>>(adj1, adj2, x, dis, P);
  k_gemm<<<dim3(2, 256), dim3(256), 0, stream>>>(x, P, WxT, WextT, biasv, out);
}